// Round 1
// baseline (410.250 us; speedup 1.0000x reference)
//
#include <hip/hip_runtime.h>
#include <hip/hip_bf16.h>

typedef unsigned short u16;
typedef __bf16 bf16x8 __attribute__((ext_vector_type(8)));
typedef float floatx4 __attribute__((ext_vector_type(4)));

#define GLOBAL_AS(p) ((const __attribute__((address_space(1))) void*)(p))
#define LDS_AS(p) ((__attribute__((address_space(3))) void*)(p))

constexpr int NB = 8192;     // batch rows
constexpr int DIN = 512;
constexpr int DH = 2048;
constexpr int DOUT = 512;
constexpr int NEXP = 8;
constexpr int ROWCAP = NB + 128;  // padded row capacity for sorted buffers

__device__ __forceinline__ u16 f2bf(float f) {
    unsigned u = __builtin_bit_cast(unsigned, f);
    unsigned r = u + 0x7FFFu + ((u >> 16) & 1u);
    return (u16)(r >> 16);
}

// ---------------- routing ----------------
__global__ void init_kernel(int* cnt, int* offs, int* curs) {
    int t = threadIdx.x;
    if (t < NEXP) { cnt[t] = 0; offs[t] = 0; curs[t] = 0; }
}

__global__ void hist_kernel(const int* __restrict__ groups, int* __restrict__ cnt) {
    __shared__ int lc[NEXP];
    if (threadIdx.x < NEXP) lc[threadIdx.x] = 0;
    __syncthreads();
    int i = blockIdx.x * 256 + threadIdx.x;
    atomicAdd(&lc[groups[i]], 1);
    __syncthreads();
    if (threadIdx.x < NEXP) atomicAdd(&cnt[threadIdx.x], lc[threadIdx.x]);
}

__global__ void scan_kernel(const int* cnt, int* offs, int* curs) {
    if (threadIdx.x == 0 && blockIdx.x == 0) {
        int run = 0;
        for (int e = 0; e < NEXP; ++e) { offs[e] = run; curs[e] = run; run += cnt[e]; }
    }
}

__global__ void scatter_kernel(const int* __restrict__ groups, int* __restrict__ curs,
                               int* __restrict__ perm) {
    int i = blockIdx.x * 256 + threadIdx.x;
    int e = groups[i];
    int pos = atomicAdd(&curs[e], 1);
    perm[pos] = i;
}

// ---------------- conversions ----------------
// gather x rows into sorted order, fp32 -> bf16
__global__ void gather_convert_x(const float* __restrict__ x, const int* __restrict__ perm,
                                 u16* __restrict__ xs) {
    int idx = blockIdx.x * 256 + threadIdx.x;   // one float4 per thread
    int pos = idx >> 7;                          // 128 float4 per row (DIN=512)
    int c = (idx & 127) * 4;
    int row = perm[pos];
    const float4 v = *(const float4*)&x[(size_t)row * DIN + c];
    ushort4 o;
    o.x = f2bf(v.x); o.y = f2bf(v.y); o.z = f2bf(v.z); o.w = f2bf(v.w);
    *(ushort4*)&xs[(size_t)pos * DIN + c] = o;
}

// src fp32 [E][R][C] -> dst bf16 [E][C][R]  (64x64 tiles, 256 threads)
__global__ void transpose_convert(const float* __restrict__ src, u16* __restrict__ dst,
                                  int R, int C) {
    __shared__ float tile[64][65];
    int e = blockIdx.z;
    int r0 = blockIdx.y * 64, c0 = blockIdx.x * 64;
    const float* s = src + (size_t)e * R * C;
    u16* d = dst + (size_t)e * R * C;
    int t = threadIdx.x;
    for (int i = 0; i < 4; ++i) {
        int r = (t >> 4) + i * 16;
        int c = (t & 15) * 4;
        const float4 v = *(const float4*)&s[(size_t)(r0 + r) * C + c0 + c];
        tile[r][c] = v.x; tile[r][c + 1] = v.y; tile[r][c + 2] = v.z; tile[r][c + 3] = v.w;
    }
    __syncthreads();
    for (int i = 0; i < 4; ++i) {
        int c = (t >> 4) + i * 16;
        int r = (t & 15) * 4;
        ushort4 o;
        o.x = f2bf(tile[r][c]); o.y = f2bf(tile[r + 1][c]);
        o.z = f2bf(tile[r + 2][c]); o.w = f2bf(tile[r + 3][c]);
        *(ushort4*)&d[(size_t)(c0 + c) * R + r0 + r] = o;
    }
}

// ---------------- GEMM (m97-style, 128x128xBK64, 16x16x32 bf16 MFMA) ----------------
// A: bf16 rows [tot][K] (sorted segment per expert), B: bf16 [E][N][K] (K-contiguous)
// PASS A (RELU_BF16): out_bf[(seg+row)*N + n] = bf16(relu(acc + bias))
// PASS B (!RELU_BF16): out_f[perm[seg+row]*N + n] = acc + bias
template <int KDIM, bool RELU_BF16>
__global__ __launch_bounds__(256) void gemm_moe(
        const u16* __restrict__ Arows, const u16* __restrict__ Bt,
        const float* __restrict__ bias, u16* __restrict__ out_bf,
        float* __restrict__ out_f, const int* __restrict__ cnt,
        const int* __restrict__ offs, const int* __restrict__ perm, int NDIM) {
    int e = blockIdx.x >> 6;
    int mt = blockIdx.x & 63;
    int count = cnt[e];
    if (mt * 128 >= count) return;
    int seg = offs[e];
    int n0 = blockIdx.y * 128;

    __shared__ u16 As[128 * 64];
    __shared__ u16 Bs[128 * 64];

    int tid = threadIdx.x;
    int l = tid & 63, w = tid >> 6;
    int wm = w & 1, wn = w >> 1;
    int q = l >> 4, li = l & 15;

    floatx4 acc[4][4];
    for (int a = 0; a < 4; ++a)
        for (int b = 0; b < 4; ++b) acc[a][b] = (floatx4)0.0f;

    const u16* Abase = Arows + (size_t)(seg + mt * 128) * KDIM;
    const u16* Bbase = Bt + ((size_t)e * NDIM + n0) * KDIM;

    for (int kt = 0; kt < KDIM / 64; ++kt) {
        __syncthreads();
        int k0 = kt * 64;
        // stage 128 rows x 64 k (A and B), XOR-swizzled 16B chunks, direct-to-LDS
        for (int j = 0; j < 4; ++j) {
            int p = j * 256 + tid;
            int row = p >> 3;
            int kc = (p & 7) ^ (row & 7);  // swizzle: slot (row, p&7) holds chunk kc
            const u16* ga = Abase + (size_t)row * KDIM + k0 + kc * 8;
            const u16* gb = Bbase + (size_t)row * KDIM + k0 + kc * 8;
            u16* la = &As[(j * 256 + w * 64) * 8];   // wave-uniform base; HW adds lane*16
            u16* lb = &Bs[(j * 256 + w * 64) * 8];
            __builtin_amdgcn_global_load_lds(GLOBAL_AS(ga), LDS_AS(la), 16, 0, 0);
            __builtin_amdgcn_global_load_lds(GLOBAL_AS(gb), LDS_AS(lb), 16, 0, 0);
        }
        __syncthreads();
        for (int s = 0; s < 2; ++s) {
            int c0 = s * 4 + q;
            bf16x8 af[4], bfr[4];
            for (int fm = 0; fm < 4; ++fm) {
                int m = wm * 64 + fm * 16 + li;
                af[fm] = *(const bf16x8*)&As[m * 64 + ((c0 ^ (m & 7)) << 3)];
            }
            for (int fn = 0; fn < 4; ++fn) {
                int n = wn * 64 + fn * 16 + li;
                bfr[fn] = *(const bf16x8*)&Bs[n * 64 + ((c0 ^ (n & 7)) << 3)];
            }
            for (int fm = 0; fm < 4; ++fm)
                for (int fn = 0; fn < 4; ++fn)
                    acc[fm][fn] = __builtin_amdgcn_mfma_f32_16x16x32_bf16(
                        af[fm], bfr[fn], acc[fm][fn], 0, 0, 0);
        }
    }

    // epilogue: C/D layout col=lane&15, row=(lane>>4)*4+reg
    for (int fn = 0; fn < 4; ++fn) {
        int ncol = n0 + wn * 64 + fn * 16 + li;
        float bv = bias[(size_t)e * NDIM + ncol];
        for (int fm = 0; fm < 4; ++fm) {
            int mrow0 = mt * 128 + wm * 64 + fm * 16 + q * 4;
            for (int r = 0; r < 4; ++r) {
                int mrow = mrow0 + r;
                if (mrow < count) {
                    float v = acc[fm][fn][r] + bv;
                    if (RELU_BF16) {
                        v = v > 0.0f ? v : 0.0f;
                        out_bf[(size_t)(seg + mrow) * NDIM + ncol] = f2bf(v);
                    } else {
                        int orow = perm[seg + mrow];
                        out_f[(size_t)orow * NDIM + ncol] = v;
                    }
                }
            }
        }
    }
}

// ---------------- launch ----------------
extern "C" void kernel_launch(void* const* d_in, const int* in_sizes, int n_in,
                              void* d_out, int out_size, void* d_ws, size_t ws_size,
                              hipStream_t stream) {
    const float* x = (const float*)d_in[0];
    const int* groups = (const int*)d_in[1];
    const float* W1 = (const float*)d_in[2];
    const float* b1 = (const float*)d_in[3];
    const float* W2 = (const float*)d_in[4];
    const float* b2 = (const float*)d_in[5];
    float* out = (float*)d_out;

    char* ws = (char*)d_ws;
    size_t o = 0;
    auto alloc = [&](size_t bytes) {
        void* p = ws + o;
        o = (o + bytes + 255) & ~(size_t)255;
        return p;
    };
    int* cnt = (int*)alloc(NEXP * 4);
    int* offs = (int*)alloc(NEXP * 4);
    int* curs = (int*)alloc(NEXP * 4);
    int* perm = (int*)alloc((size_t)ROWCAP * 4);
    u16* xs = (u16*)alloc((size_t)ROWCAP * DIN * 2);
    u16* w1t = (u16*)alloc((size_t)NEXP * DIN * DH * 2);
    u16* w2t = (u16*)alloc((size_t)NEXP * DH * DOUT * 2);
    u16* hs = (u16*)alloc((size_t)ROWCAP * DH * 2);
    // total ws use ~77 MB

    init_kernel<<<1, 64, 0, stream>>>(cnt, offs, curs);
    hist_kernel<<<NB / 256, 256, 0, stream>>>(groups, cnt);
    scan_kernel<<<1, 64, 0, stream>>>(cnt, offs, curs);
    scatter_kernel<<<NB / 256, 256, 0, stream>>>(groups, curs, perm);
    gather_convert_x<<<(NB * (DIN / 4)) / 256, 256, 0, stream>>>(x, perm, xs);
    transpose_convert<<<dim3(DH / 64, DIN / 64, NEXP), 256, 0, stream>>>(W1, w1t, DIN, DH);
    transpose_convert<<<dim3(DOUT / 64, DH / 64, NEXP), 256, 0, stream>>>(W2, w2t, DH, DOUT);

    // pass A: h = relu(x @ W1 + b1)   M=cnt[e], N=2048, K=512
    gemm_moe<DIN, true><<<dim3(NEXP * 64, DH / 128), 256, 0, stream>>>(
        xs, w1t, b1, hs, nullptr, cnt, offs, perm, DH);
    // pass B: out = h @ W2 + b2       M=cnt[e], N=512, K=2048
    gemm_moe<DH, false><<<dim3(NEXP * 64, DOUT / 128), 256, 0, stream>>>(
        hs, w2t, b2, nullptr, out, cnt, offs, perm, DOUT);
}

// Round 2
// 357.626 us; speedup vs baseline: 1.1471x; 1.1471x over previous
//
#include <hip/hip_runtime.h>
#include <hip/hip_bf16.h>

typedef unsigned short u16;
typedef __bf16 bf16x8 __attribute__((ext_vector_type(8)));
typedef float floatx4 __attribute__((ext_vector_type(4)));

#define GLOBAL_AS(p) ((const __attribute__((address_space(1))) void*)(p))
#define LDS_AS(p) ((__attribute__((address_space(3))) void*)(p))

constexpr int NB = 8192;     // batch rows
constexpr int DIN = 512;
constexpr int DH = 2048;
constexpr int DOUT = 512;
constexpr int NEXP = 8;
constexpr int ROWCAP = NB + 128;  // padded row capacity for sorted buffers
constexpr int MAXMT = 71;         // worst-case sum of ceil(cnt[e]/128): 64 + 7

__device__ __forceinline__ u16 f2bf(float f) {
    unsigned u = __builtin_bit_cast(unsigned, f);
    unsigned r = u + 0x7FFFu + ((u >> 16) & 1u);
    return (u16)(r >> 16);
}

// ---------------- routing ----------------
__global__ void init_kernel(int* cnt, int* offs, int* curs) {
    int t = threadIdx.x;
    if (t < NEXP) { cnt[t] = 0; offs[t] = 0; curs[t] = 0; }
}

__global__ void hist_kernel(const int* __restrict__ groups, int* __restrict__ cnt) {
    __shared__ int lc[NEXP];
    if (threadIdx.x < NEXP) lc[threadIdx.x] = 0;
    __syncthreads();
    int i = blockIdx.x * 256 + threadIdx.x;
    atomicAdd(&lc[groups[i]], 1);
    __syncthreads();
    if (threadIdx.x < NEXP) atomicAdd(&cnt[threadIdx.x], lc[threadIdx.x]);
}

__global__ void scan_kernel(const int* cnt, int* offs, int* curs, int* tstart) {
    if (threadIdx.x == 0 && blockIdx.x == 0) {
        int run = 0, trun = 0;
        for (int e = 0; e < NEXP; ++e) {
            offs[e] = run; curs[e] = run; run += cnt[e];
            tstart[e] = trun; trun += (cnt[e] + 127) >> 7;
        }
        tstart[NEXP] = trun;
    }
}

__global__ void scatter_kernel(const int* __restrict__ groups, int* __restrict__ curs,
                               int* __restrict__ perm) {
    int i = blockIdx.x * 256 + threadIdx.x;
    int e = groups[i];
    int pos = atomicAdd(&curs[e], 1);
    perm[pos] = i;
}

// ---------------- conversions ----------------
__global__ void gather_convert_x(const float* __restrict__ x, const int* __restrict__ perm,
                                 u16* __restrict__ xs) {
    int idx = blockIdx.x * 256 + threadIdx.x;   // one float4 per thread
    int pos = idx >> 7;                          // 128 float4 per row (DIN=512)
    int c = (idx & 127) * 4;
    int row = perm[pos];
    const float4 v = *(const float4*)&x[(size_t)row * DIN + c];
    ushort4 o;
    o.x = f2bf(v.x); o.y = f2bf(v.y); o.z = f2bf(v.z); o.w = f2bf(v.w);
    *(ushort4*)&xs[(size_t)pos * DIN + c] = o;
}

// src fp32 [E][R][C] -> dst bf16 [E][C][R]  (64x64 tiles, 256 threads)
__global__ void transpose_convert(const float* __restrict__ src, u16* __restrict__ dst,
                                  int R, int C) {
    __shared__ float tile[64][65];
    int e = blockIdx.z;
    int r0 = blockIdx.y * 64, c0 = blockIdx.x * 64;
    const float* s = src + (size_t)e * R * C;
    u16* d = dst + (size_t)e * R * C;
    int t = threadIdx.x;
    for (int i = 0; i < 4; ++i) {
        int r = (t >> 4) + i * 16;
        int c = (t & 15) * 4;
        const float4 v = *(const float4*)&s[(size_t)(r0 + r) * C + c0 + c];
        tile[r][c] = v.x; tile[r][c + 1] = v.y; tile[r][c + 2] = v.z; tile[r][c + 3] = v.w;
    }
    __syncthreads();
    for (int i = 0; i < 4; ++i) {
        int c = (t >> 4) + i * 16;
        int r = (t & 15) * 4;
        ushort4 o;
        o.x = f2bf(tile[r][c]); o.y = f2bf(tile[r + 1][c]);
        o.z = f2bf(tile[r + 2][c]); o.w = f2bf(tile[r + 3][c]);
        *(ushort4*)&d[(size_t)(c0 + c) * R + r0 + r] = o;
    }
}

// out[b][:] = b2[groups[b]][:]  (pass B accumulates on top via atomics)
__global__ void init_out(const int* __restrict__ groups, const float* __restrict__ b2,
                         float* __restrict__ out) {
    int idx = blockIdx.x * 256 + threadIdx.x;   // one float4 per thread
    int b = idx >> 7;                            // 128 float4 per row (DOUT=512)
    int c = (idx & 127) * 4;
    int g = groups[b];
    *(float4*)&out[(size_t)b * DOUT + c] = *(const float4*)&b2[(size_t)g * DOUT + c];
}

// ---------------- GEMM (128x128 x BK64, 16x16x32 bf16 MFMA, dense tile map) ----------------
// A: bf16 rows (sorted segments), stride KSTRIDE. B: bf16 [E][N][K], stride KSTRIDE.
// RELU=true : out_bf[(seg+row)*NDIM + n] = bf16(relu(acc + bias[e][n]))   (pass A)
// RELU=false: atomicAdd(&out_f[perm[seg+row]*NDIM + n], acc)              (pass B, k-split)
template <bool RELU>
__global__ __launch_bounds__(256) void gemm_tiles(
        const u16* __restrict__ Arows, const u16* __restrict__ Bt,
        const float* __restrict__ bias, u16* __restrict__ out_bf,
        float* __restrict__ out_f, const int* __restrict__ cnt,
        const int* __restrict__ offs, const int* __restrict__ tstart,
        const int* __restrict__ perm, int NDIM, int KSTRIDE) {
    int mt_flat = blockIdx.x;
    if (mt_flat >= tstart[NEXP]) return;   // few, trailing-interleaved dead blocks
    int e = 0;
    while (mt_flat >= tstart[e + 1]) ++e;
    int mt = mt_flat - tstart[e];
    int count = cnt[e];
    int seg = offs[e];
    int n0 = blockIdx.y * 128;
    int kbase = blockIdx.z * 512;          // k-split (pass B); 0 for pass A

    __shared__ u16 As[128 * 64];
    __shared__ u16 Bs[128 * 64];

    int tid = threadIdx.x;
    int l = tid & 63, w = tid >> 6;
    int wm = w & 1, wn = w >> 1;
    int q = l >> 4, li = l & 15;

    floatx4 acc[4][4];
    for (int a = 0; a < 4; ++a)
        for (int b = 0; b < 4; ++b) acc[a][b] = (floatx4)0.0f;

    const u16* Abase = Arows + (size_t)(seg + mt * 128) * KSTRIDE + kbase;
    const u16* Bbase = Bt + ((size_t)e * NDIM + n0) * KSTRIDE + kbase;

    for (int kt = 0; kt < 8; ++kt) {       // 8 ktiles x 64 = K=512 window
        __syncthreads();
        int k0 = kt * 64;
        for (int j = 0; j < 4; ++j) {
            int p = j * 256 + tid;
            int row = p >> 3;
            int kc = (p & 7) ^ (row & 7);  // xor-swizzled 16B chunks
            const u16* ga = Abase + (size_t)row * KSTRIDE + k0 + kc * 8;
            const u16* gb = Bbase + (size_t)row * KSTRIDE + k0 + kc * 8;
            u16* la = &As[(j * 256 + w * 64) * 8];   // wave-uniform base; HW adds lane*16
            u16* lb = &Bs[(j * 256 + w * 64) * 8];
            __builtin_amdgcn_global_load_lds(GLOBAL_AS(ga), LDS_AS(la), 16, 0, 0);
            __builtin_amdgcn_global_load_lds(GLOBAL_AS(gb), LDS_AS(lb), 16, 0, 0);
        }
        __syncthreads();
        for (int s = 0; s < 2; ++s) {
            int c0 = s * 4 + q;
            bf16x8 af[4], bfr[4];
            for (int fm = 0; fm < 4; ++fm) {
                int m = wm * 64 + fm * 16 + li;
                af[fm] = *(const bf16x8*)&As[m * 64 + ((c0 ^ (m & 7)) << 3)];
            }
            for (int fn = 0; fn < 4; ++fn) {
                int n = wn * 64 + fn * 16 + li;
                bfr[fn] = *(const bf16x8*)&Bs[n * 64 + ((c0 ^ (n & 7)) << 3)];
            }
            for (int fm = 0; fm < 4; ++fm)
                for (int fn = 0; fn < 4; ++fn)
                    acc[fm][fn] = __builtin_amdgcn_mfma_f32_16x16x32_bf16(
                        af[fm], bfr[fn], acc[fm][fn], 0, 0, 0);
        }
    }

    // epilogue: C/D layout col=lane&15, row=(lane>>4)*4+reg
    for (int fn = 0; fn < 4; ++fn) {
        int ncol = n0 + wn * 64 + fn * 16 + li;
        float bv = RELU ? bias[(size_t)e * NDIM + ncol] : 0.0f;
        for (int fm = 0; fm < 4; ++fm) {
            int mrow0 = mt * 128 + wm * 64 + fm * 16 + q * 4;
            for (int r = 0; r < 4; ++r) {
                int mrow = mrow0 + r;
                if (mrow < count) {
                    float v = acc[fm][fn][r] + bv;
                    if (RELU) {
                        v = v > 0.0f ? v : 0.0f;
                        out_bf[(size_t)(seg + mrow) * NDIM + ncol] = f2bf(v);
                    } else {
                        int orow = perm[seg + mrow];
                        atomicAdd(&out_f[(size_t)orow * NDIM + ncol], v);
                    }
                }
            }
        }
    }
}

// ---------------- launch ----------------
extern "C" void kernel_launch(void* const* d_in, const int* in_sizes, int n_in,
                              void* d_out, int out_size, void* d_ws, size_t ws_size,
                              hipStream_t stream) {
    const float* x = (const float*)d_in[0];
    const int* groups = (const int*)d_in[1];
    const float* W1 = (const float*)d_in[2];
    const float* b1 = (const float*)d_in[3];
    const float* W2 = (const float*)d_in[4];
    const float* b2 = (const float*)d_in[5];
    float* out = (float*)d_out;

    char* ws = (char*)d_ws;
    size_t o = 0;
    auto alloc = [&](size_t bytes) {
        void* p = ws + o;
        o = (o + bytes + 255) & ~(size_t)255;
        return p;
    };
    int* cnt = (int*)alloc(NEXP * 4);
    int* offs = (int*)alloc(NEXP * 4);
    int* curs = (int*)alloc(NEXP * 4);
    int* tstart = (int*)alloc((NEXP + 1) * 4);
    int* perm = (int*)alloc((size_t)ROWCAP * 4);
    u16* xs = (u16*)alloc((size_t)ROWCAP * DIN * 2);
    u16* w1t = (u16*)alloc((size_t)NEXP * DIN * DH * 2);
    u16* w2t = (u16*)alloc((size_t)NEXP * DH * DOUT * 2);
    u16* hs = (u16*)alloc((size_t)ROWCAP * DH * 2);

    init_kernel<<<1, 64, 0, stream>>>(cnt, offs, curs);
    hist_kernel<<<NB / 256, 256, 0, stream>>>(groups, cnt);
    scan_kernel<<<1, 64, 0, stream>>>(cnt, offs, curs, tstart);
    scatter_kernel<<<NB / 256, 256, 0, stream>>>(groups, curs, perm);
    gather_convert_x<<<(NB * (DIN / 4)) / 256, 256, 0, stream>>>(x, perm, xs);
    transpose_convert<<<dim3(DH / 64, DIN / 64, NEXP), 256, 0, stream>>>(W1, w1t, DIN, DH);
    transpose_convert<<<dim3(DOUT / 64, DH / 64, NEXP), 256, 0, stream>>>(W2, w2t, DH, DOUT);
    init_out<<<(NB * (DOUT / 4)) / 256, 256, 0, stream>>>(groups, b2, out);

    // pass A: h = relu(x @ W1 + b1)   dense m-tiles x 16 n-tiles, K=512
    gemm_tiles<true><<<dim3(MAXMT, DH / 128, 1), 256, 0, stream>>>(
        xs, w1t, b1, hs, nullptr, cnt, offs, tstart, perm, DH, DIN);
    // pass B: out += h @ W2           dense m-tiles x 4 n-tiles x 4 k-splits
    gemm_tiles<false><<<dim3(MAXMT, DOUT / 128, DH / 512), 256, 0, stream>>>(
        hs, w2t, nullptr, nullptr, out, cnt, offs, tstart, perm, DOUT, DH);
}

// Round 3
// 284.082 us; speedup vs baseline: 1.4441x; 1.2589x over previous
//
#include <hip/hip_runtime.h>
#include <hip/hip_bf16.h>

typedef unsigned short u16;
typedef __bf16 bf16x8 __attribute__((ext_vector_type(8)));
typedef float floatx4 __attribute__((ext_vector_type(4)));

#define GLOBAL_AS(p) ((const __attribute__((address_space(1))) void*)(p))
#define LDS_AS(p) ((__attribute__((address_space(3))) void*)(p))

constexpr int NB = 8192;
constexpr int DIN = 512;
constexpr int DH = 2048;
constexpr int DOUT = 512;
constexpr int NEXP = 8;
constexpr int ROWCAP = NB + 128;
constexpr int MTCAP = 64;   // unconditional coverage: one expert could own all rows

__device__ __forceinline__ u16 f2bf(float f) {
    unsigned u = __builtin_bit_cast(unsigned, f);
    unsigned r = u + 0x7FFFu + ((u >> 16) & 1u);
    return (u16)(r >> 16);
}

// ---------------- routing: hist + scan + scatter in ONE single-block kernel ----------------
__global__ void route_kernel(const int* __restrict__ groups, int* __restrict__ cnt,
                             int* __restrict__ offs, int* __restrict__ perm) {
    __shared__ int lc[NEXP];
    __shared__ int lcur[NEXP];
    int t = threadIdx.x;
    if (t < NEXP) lc[t] = 0;
    __syncthreads();
    for (int i = t; i < NB; i += 256) atomicAdd(&lc[groups[i]], 1);
    __syncthreads();
    if (t == 0) {
        int run = 0;
        for (int e = 0; e < NEXP; ++e) {
            cnt[e] = lc[e]; offs[e] = run; lcur[e] = run; run += lc[e];
        }
    }
    __syncthreads();
    for (int i = t; i < NB; i += 256) {
        int e = groups[i];
        int pos = atomicAdd(&lcur[e], 1);
        perm[pos] = i;
    }
}

// ---------------- conversions ----------------
__global__ void gather_convert_x(const float* __restrict__ x, const int* __restrict__ perm,
                                 u16* __restrict__ xs) {
    int idx = blockIdx.x * 256 + threadIdx.x;   // one float4 per thread
    int pos = idx >> 7;                          // 128 float4 per row (DIN=512)
    int c = (idx & 127) * 4;
    int row = perm[pos];
    const float4 v = *(const float4*)&x[(size_t)row * DIN + c];
    ushort4 o;
    o.x = f2bf(v.x); o.y = f2bf(v.y); o.z = f2bf(v.z); o.w = f2bf(v.w);
    *(ushort4*)&xs[(size_t)pos * DIN + c] = o;
}

// src fp32 [E][R][C] -> dst bf16 [E][C][R]
__global__ void transpose_convert(const float* __restrict__ src, u16* __restrict__ dst,
                                  int R, int C) {
    __shared__ float tile[64][65];
    int e = blockIdx.z;
    int r0 = blockIdx.y * 64, c0 = blockIdx.x * 64;
    const float* s = src + (size_t)e * R * C;
    u16* d = dst + (size_t)e * R * C;
    int t = threadIdx.x;
    for (int i = 0; i < 4; ++i) {
        int r = (t >> 4) + i * 16;
        int c = (t & 15) * 4;
        const float4 v = *(const float4*)&s[(size_t)(r0 + r) * C + c0 + c];
        tile[r][c] = v.x; tile[r][c + 1] = v.y; tile[r][c + 2] = v.z; tile[r][c + 3] = v.w;
    }
    __syncthreads();
    for (int i = 0; i < 4; ++i) {
        int c = (t >> 4) + i * 16;
        int r = (t & 15) * 4;
        ushort4 o;
        o.x = f2bf(tile[r][c]); o.y = f2bf(tile[r + 1][c]);
        o.z = f2bf(tile[r + 2][c]); o.w = f2bf(tile[r + 3][c]);
        *(ushort4*)&d[(size_t)(c0 + c) * R + r0 + r] = o;
    }
}

// out[b][:] = b2[groups[b]][:]  (pass B accumulates via atomics)
__global__ void init_out(const int* __restrict__ groups, const float* __restrict__ b2,
                         float* __restrict__ out) {
    int idx = blockIdx.x * 256 + threadIdx.x;
    int b = idx >> 7;
    int c = (idx & 127) * 4;
    int g = groups[b];
    *(float4*)&out[(size_t)b * DOUT + c] = *(const float4*)&b2[(size_t)g * DOUT + c];
}

// ---------------- GEMM building blocks ----------------
__device__ __forceinline__ void stage_tile(const u16* Abase, const u16* Bbase, int KSTRIDE,
                                           int k0, u16* As, u16* Bs, int tid, int w) {
    for (int j = 0; j < 4; ++j) {
        int p = j * 256 + tid;
        int row = p >> 3;
        int kc = (p & 7) ^ (row & 7);  // xor-swizzled 16B chunks
        const u16* ga = Abase + (size_t)row * KSTRIDE + k0 + kc * 8;
        const u16* gb = Bbase + (size_t)row * KSTRIDE + k0 + kc * 8;
        u16* la = &As[(j * 256 + w * 64) * 8];   // wave-uniform base; HW adds lane*16
        u16* lb = &Bs[(j * 256 + w * 64) * 8];
        __builtin_amdgcn_global_load_lds(GLOBAL_AS(ga), LDS_AS(la), 16, 0, 0);
        __builtin_amdgcn_global_load_lds(GLOBAL_AS(gb), LDS_AS(lb), 16, 0, 0);
    }
}

__device__ __forceinline__ void compute_tile(const u16* As, const u16* Bs, floatx4 acc[4][4],
                                             int wm, int wn, int q, int li) {
    for (int s = 0; s < 2; ++s) {
        int c0 = s * 4 + q;
        bf16x8 af[4], bfr[4];
        for (int fm = 0; fm < 4; ++fm) {
            int m = wm * 64 + fm * 16 + li;
            af[fm] = *(const bf16x8*)&As[m * 64 + ((c0 ^ (m & 7)) << 3)];
        }
        for (int fn = 0; fn < 4; ++fn) {
            int n = wn * 64 + fn * 16 + li;
            bfr[fn] = *(const bf16x8*)&Bs[n * 64 + ((c0 ^ (n & 7)) << 3)];
        }
        for (int fm = 0; fm < 4; ++fm)
            for (int fn = 0; fn < 4; ++fn)
                acc[fm][fn] = __builtin_amdgcn_mfma_f32_16x16x32_bf16(
                    af[fm], bfr[fn], acc[fm][fn], 0, 0, 0);
    }
}

// 128x128 tile, K-window = 512 (8 ktiles of 64), double-buffered LDS.
// Grid is 1-D, expert in low 3 bits (XCD affinity), live blocks dense at front.
// RELU=true : pass A, h = relu(x@W1+b1) -> bf16; decode nt from bits [3..6] (16 n-tiles)
// RELU=false: pass B, out += h@W2 (k-split 4, atomicAdd); decode nt (4) and ksplit (4)
template <bool RELU>
__global__ __launch_bounds__(256) void gemm_tiles(
        const u16* __restrict__ Arows, const u16* __restrict__ Bt,
        const float* __restrict__ bias, u16* __restrict__ out_bf,
        float* __restrict__ out_f, const int* __restrict__ cnt,
        const int* __restrict__ offs, const int* __restrict__ perm,
        int NDIM, int KSTRIDE) {
    int bx = blockIdx.x;
    int e = bx & 7;
    int r = bx >> 3;
    int nt, kbase, mt;
    if (RELU) {
        nt = r & 15; mt = r >> 4; kbase = 0;
    } else {
        nt = r & 3; r >>= 2;
        kbase = (r & 3) * 512; mt = r >> 2;
    }
    int count = cnt[e];
    if (mt * 128 >= count) return;   // dead tail, exits immediately
    int seg = offs[e];
    int n0 = nt * 128;

    __shared__ u16 As0[128 * 64];
    __shared__ u16 Bs0[128 * 64];
    __shared__ u16 As1[128 * 64];
    __shared__ u16 Bs1[128 * 64];

    int tid = threadIdx.x;
    int l = tid & 63, w = tid >> 6;
    int wm = w & 1, wn = w >> 1;
    int q = l >> 4, li = l & 15;

    floatx4 acc[4][4];
    for (int a = 0; a < 4; ++a)
        for (int b = 0; b < 4; ++b) acc[a][b] = (floatx4)0.0f;

    const u16* Abase = Arows + (size_t)(seg + mt * 128) * KSTRIDE + kbase;
    const u16* Bbase = Bt + ((size_t)e * NDIM + n0) * KSTRIDE + kbase;

    // software pipeline: prefetch(kt+1) issued right after barrier, before compute(kt)
    stage_tile(Abase, Bbase, KSTRIDE, 0, As0, Bs0, tid, w);
    for (int kt = 0; kt < 8; kt += 2) {
        __syncthreads();
        if (kt + 1 < 8) stage_tile(Abase, Bbase, KSTRIDE, (kt + 1) * 64, As1, Bs1, tid, w);
        compute_tile(As0, Bs0, acc, wm, wn, q, li);
        __syncthreads();
        if (kt + 2 < 8) stage_tile(Abase, Bbase, KSTRIDE, (kt + 2) * 64, As0, Bs0, tid, w);
        compute_tile(As1, Bs1, acc, wm, wn, q, li);
    }

    // epilogue: C/D layout col=lane&15, row=(lane>>4)*4+reg
    for (int fn = 0; fn < 4; ++fn) {
        int ncol = n0 + wn * 64 + fn * 16 + li;
        float bv = RELU ? bias[(size_t)e * NDIM + ncol] : 0.0f;
        for (int fm = 0; fm < 4; ++fm) {
            int mrow0 = mt * 128 + wm * 64 + fm * 16 + q * 4;
            for (int rr = 0; rr < 4; ++rr) {
                int mrow = mrow0 + rr;
                if (mrow < count) {
                    float v = acc[fm][fn][rr] + bv;
                    if (RELU) {
                        v = v > 0.0f ? v : 0.0f;
                        out_bf[(size_t)(seg + mrow) * NDIM + ncol] = f2bf(v);
                    } else {
                        int orow = perm[seg + mrow];
                        atomicAdd(&out_f[(size_t)orow * NDIM + ncol], v);
                    }
                }
            }
        }
    }
}

// ---------------- launch ----------------
extern "C" void kernel_launch(void* const* d_in, const int* in_sizes, int n_in,
                              void* d_out, int out_size, void* d_ws, size_t ws_size,
                              hipStream_t stream) {
    const float* x = (const float*)d_in[0];
    const int* groups = (const int*)d_in[1];
    const float* W1 = (const float*)d_in[2];
    const float* b1 = (const float*)d_in[3];
    const float* W2 = (const float*)d_in[4];
    const float* b2 = (const float*)d_in[5];
    float* out = (float*)d_out;

    char* ws = (char*)d_ws;
    size_t o = 0;
    auto alloc = [&](size_t bytes) {
        void* p = ws + o;
        o = (o + bytes + 255) & ~(size_t)255;
        return p;
    };
    int* cnt = (int*)alloc(NEXP * 4);
    int* offs = (int*)alloc(NEXP * 4);
    int* perm = (int*)alloc((size_t)ROWCAP * 4);
    u16* xs = (u16*)alloc((size_t)ROWCAP * DIN * 2);
    u16* w1t = (u16*)alloc((size_t)NEXP * DIN * DH * 2);
    u16* w2t = (u16*)alloc((size_t)NEXP * DH * DOUT * 2);
    u16* hs = (u16*)alloc((size_t)ROWCAP * DH * 2);

    route_kernel<<<1, 256, 0, stream>>>(groups, cnt, offs, perm);
    gather_convert_x<<<(NB * (DIN / 4)) / 256, 256, 0, stream>>>(x, perm, xs);
    transpose_convert<<<dim3(DH / 64, DIN / 64, NEXP), 256, 0, stream>>>(W1, w1t, DIN, DH);
    transpose_convert<<<dim3(DOUT / 64, DH / 64, NEXP), 256, 0, stream>>>(W2, w2t, DH, DOUT);
    init_out<<<(NB * (DOUT / 4)) / 256, 256, 0, stream>>>(groups, b2, out);

    // pass A: h = relu(x @ W1 + b1); grid = 8 experts x 16 n-tiles x MTCAP m-tiles (1-D)
    gemm_tiles<true><<<dim3(NEXP * 16 * MTCAP), 256, 0, stream>>>(
        xs, w1t, b1, hs, nullptr, cnt, offs, perm, DH, DIN);
    // pass B: out += h @ W2; grid = 8 experts x 4 n-tiles x 4 k-splits x MTCAP (1-D)
    gemm_tiles<false><<<dim3(NEXP * 4 * 4 * MTCAP), 256, 0, stream>>>(
        hs, w2t, nullptr, nullptr, out, cnt, offs, perm, DOUT, DH);
}